// Round 11
// baseline (377.511 us; speedup 1.0000x reference)
//
#include <hip/hip_runtime.h>
#include <hip/hip_bf16.h>
#include <stdint.h>

#define N_OUT 512
#define N_IN 64
#define D_TOT 576               // N_IN + N_OUT
#define BM 64                   // batch rows per block
#define BN 256                  // cols per block (2 col-blocks)
#define ROW_BYTES (D_TOT * 2)   // 1152 bytes per LDS x row (bf16)
#define BATCH 131072

// LDS layout (dynamic, 141312 B total -> 1 block/CU):
//   [0,65536)        wbuf[2][2mat][4lg][256col][16B]  weight double buffer
//   [65536,139264)   xt[64][1152]                     x = cat(c,X) bf16, XOR-swizzled
//   [139264,141312)  ldsum[8][64] f32                 log_det cross-wave reduce
#define WOFF 0
#define XOFF 65536
#define SOFF 139264
#define LDS_TOTAL 141312

typedef __attribute__((ext_vector_type(8))) short short8_t;   // 8 x bf16
typedef __attribute__((ext_vector_type(4))) short short4_t;   // 4 x bf16
typedef __attribute__((ext_vector_type(4))) float f32x4;
typedef unsigned short u16;

__device__ __forceinline__ u16 f2bf(float f) {
    __hip_bfloat16 h = __float2bfloat16(f);
    return *reinterpret_cast<u16*>(&h);
}
__device__ __forceinline__ float bf2f(u16 u) {
    union { uint32_t u; float f; } v;
    v.u = ((uint32_t)u) << 16;
    return v.f;
}

// Prep: masked bf16 weights, k-major fragment layout (unchanged since R2):
//   dst[((kk*4 + lg) * 512 + col) * 8 + j] holds W[col][kk*32 + lg*8 + j]
__global__ void prep_weights_kernel(const float* __restrict__ PA,
                                    const float* __restrict__ PB,
                                    u16* __restrict__ WA,
                                    u16* __restrict__ WB) {
    const int col = blockIdx.x;
    const int lim = N_IN + col;
    const float* pa = PA + (size_t)col * D_TOT;
    const float* pb = PB + (size_t)col * D_TOT;
    for (int k = threadIdx.x; k < D_TOT; k += blockDim.x) {
        int kk = k >> 5, lg = (k >> 3) & 3, j = k & 7;
        size_t dst = ((size_t)(kk * 4 + lg) * N_OUT + col) * 8 + j;
        bool valid = (k < lim);
        WA[dst] = valid ? f2bf(pa[k]) : (u16)0;
        WB[dst] = valid ? f2bf(pb[k]) : (u16)0;
    }
}

// Merge per-cb log_det partials: LD[r] = PS[0][r] + PS[1][r]
__global__ void ld_merge_kernel(const float* __restrict__ PS,
                                float* __restrict__ LD) {
    int i = blockIdx.x * 256 + threadIdx.x;
    LD[i] = PS[i] + PS[BATCH + i];
}

// Main kernel. 512 threads / 8 waves, 1 block/CU (141 KB LDS).
// R11 diagnosis: per-CU VMEM/TA request path was the config-invariant
// serializer (~600-850 cyc per K-round at any occupancy). Weights now go
// HBM/L2 -> LDS once per block per K-step via global_load_lds (4 instrs/thread
// /K-step for the whole block), double-buffered T3-minimum 2-phase; waves read
// fragments from LDS. X is staged incrementally (slab kk+1 during kk) so its
// HBM fetch overlaps the MFMA phases instead of serializing as a prologue.
__global__ __launch_bounds__(512)
void maf_main_kernel(const float* __restrict__ X,
                     const float* __restrict__ Cc,
                     const u16* __restrict__ WA,
                     const u16* __restrict__ WB,
                     float* __restrict__ Z,
                     float* __restrict__ PS) {
    extern __shared__ char smem[];
    char* wlds = smem + WOFF;
    char* xt   = smem + XOFF;
    float* ldsum = (float*)(smem + SOFF);

    const int tid = threadIdx.x;
    const int bid = blockIdx.x;
    const int cb  = bid & 1;            // adjacent blocks share rows -> X L2/L3 reuse
    const int rb  = bid >> 1;
    const int r0  = rb * BM;
    const int cbase = cb * BN;

    const int wid  = tid >> 6;
    const int lane = tid & 63;
    const int lr = lane & 15;   // fragment row (A) / col (B,C)
    const int lg = lane >> 4;   // k sub-block (A,B) / row quad (C)

    const int T0 = (cb << 4) + wid;        // this wave's two 16-col tiles
    const int T1 = (cb << 4) + 15 - wid;   // (causal-balanced pairing)
    const int ks0 = (111 + 16 * T0) >> 5;  // K-steps needed by tile T
    const int ks1 = (111 + 16 * T1) >> 5;
    const int kmax = 10 + 8 * cb;          // block-wide K-steps (= ks of last tile)

    const int xrow = tid >> 3, xq = tid & 7;   // X-slab staging role (f32x4/thread)

    // ---- prologue: X slab 0 + weight K-step 0 into buf 0 ----
    {
        int kb = xq * 4;   // slab 0: k in [0,32) -> c
        f32x4 v = __builtin_nontemporal_load(
            (const f32x4*)(Cc + (size_t)(r0 + xrow) * N_IN + kb));
        short4_t p;
        p[0] = (short)f2bf(v[0]); p[1] = (short)f2bf(v[1]);
        p[2] = (short)f2bf(v[2]); p[3] = (short)f2bf(v[3]);
        int addr = (xrow * ROW_BYTES + kb * 2) ^ ((xrow & 7) << 4);
        *(short4_t*)(xt + addr) = p;
    }
    #pragma unroll
    for (int i = 0; i < 4; ++i) {
        int f = i * 512 + tid;
        int mat = f >> 10, q = f & 1023;
        int lg2 = q >> 8, col = q & 255;
        const u16* g = (mat ? WB : WA) + ((size_t)lg2 * N_OUT + cbase + col) * 8; // kk=0
        char* l = wlds + f * 16;
        __builtin_amdgcn_global_load_lds(
            (const __attribute__((address_space(1))) uint32_t*)g,
            (__attribute__((address_space(3))) uint32_t*)l, 16, 0, 0);
    }
    __syncthreads();

    f32x4 aE0[4], aV0[4], aE1[4], aV1[4];
    #pragma unroll
    for (int m = 0; m < 4; ++m) {
        aE0[m] = (f32x4)(0.0f); aV0[m] = (f32x4)(0.0f);
        aE1[m] = (f32x4)(0.0f); aV1[m] = (f32x4)(0.0f);
    }

    const int cl0 = ((T0 & 15) << 4) + lr;   // local col of tile0 fragment
    const int cl1 = ((T1 & 15) << 4) + lr;

    int buf = 0;
    for (int kk = 0; kk < kmax; ++kk) {
        const int s = kk + 1;
        // 1) issue next X slab's global load early (lands under MFMA phase)
        f32x4 xv;
        if (s < kmax) {
            int kb = s * 32 + xq * 4;
            const float* src = (s < 2)
                ? (Cc + (size_t)(r0 + xrow) * N_IN + kb)
                : (X + (size_t)(r0 + xrow) * N_OUT + (kb - 64));
            xv = __builtin_nontemporal_load((const f32x4*)src);
        }
        // 2) issue next weight slab into the other buffer
        if (s < kmax) {
            #pragma unroll
            for (int i = 0; i < 4; ++i) {
                int f = i * 512 + tid;
                int mat = f >> 10, q = f & 1023;
                int lg2 = q >> 8, col = q & 255;
                const u16* g = (mat ? WB : WA)
                    + ((size_t)((s << 2) + lg2) * N_OUT + cbase + col) * 8;
                char* l = wlds + (buf ^ 1) * 32768 + f * 16;
                __builtin_amdgcn_global_load_lds(
                    (const __attribute__((address_space(1))) uint32_t*)g,
                    (__attribute__((address_space(3))) uint32_t*)l, 16, 0, 0);
            }
        }
        // 3) compute from current buffer
        const char* wb_ = wlds + buf * 32768;
        short8_t a[4];
        #pragma unroll
        for (int m = 0; m < 4; ++m) {
            int row = (m << 4) + lr;
            int addr = (row * ROW_BYTES + kk * 64 + lg * 16) ^ ((row & 7) << 4);
            a[m] = *(const short8_t*)(xt + addr);
        }
        if (kk < ks0) {
            short8_t we = *(const short8_t*)(wb_ + ((lg << 8) + cl0) * 16);
            short8_t wv = *(const short8_t*)(wb_ + 16384 + ((lg << 8) + cl0) * 16);
            #pragma unroll
            for (int m = 0; m < 4; ++m) {
                aE0[m] = __builtin_amdgcn_mfma_f32_16x16x32_bf16(a[m], we, aE0[m], 0, 0, 0);
                aV0[m] = __builtin_amdgcn_mfma_f32_16x16x32_bf16(a[m], wv, aV0[m], 0, 0, 0);
            }
        }
        if (kk < ks1) {
            short8_t we = *(const short8_t*)(wb_ + ((lg << 8) + cl1) * 16);
            short8_t wv = *(const short8_t*)(wb_ + 16384 + ((lg << 8) + cl1) * 16);
            #pragma unroll
            for (int m = 0; m < 4; ++m) {
                aE1[m] = __builtin_amdgcn_mfma_f32_16x16x32_bf16(a[m], we, aE1[m], 0, 0, 0);
                aV1[m] = __builtin_amdgcn_mfma_f32_16x16x32_bf16(a[m], wv, aV1[m], 0, 0, 0);
            }
        }
        // 4) write next X slab to LDS (disjoint from slab kk being read)
        if (s < kmax) {
            int kb = s * 32 + xq * 4;
            short4_t p;
            p[0] = (short)f2bf(xv[0]); p[1] = (short)f2bf(xv[1]);
            p[2] = (short)f2bf(xv[2]); p[3] = (short)f2bf(xv[3]);
            int addr = (xrow * ROW_BYTES + kb * 2) ^ ((xrow & 7) << 4);
            *(short4_t*)(xt + addr) = p;
        }
        __syncthreads();   // drains gload_lds (vmcnt) + LDS writes; swap buffers
        buf ^= 1;
    }

    // ---- epilogue: z = X*exp(A)+Bv ; log_det partial rowsums ----
    float part[4][4];
    #pragma unroll
    for (int m = 0; m < 4; ++m)
        #pragma unroll
        for (int j = 0; j < 4; ++j) part[m][j] = 0.0f;

    const int gcol0 = (T0 << 4) + lr;
    const int gcol1 = (T1 << 4) + lr;
    #pragma unroll
    for (int m = 0; m < 4; ++m) {
        #pragma unroll
        for (int j = 0; j < 4; ++j) {
            int row = (m << 4) + (lg << 2) + j;
            int swz = (row & 7) << 4;
            {
                float Av = aE0[m][j], Bv = aV0[m][j];
                int xb = (row * ROW_BYTES + (N_IN + gcol0) * 2) ^ swz;
                float Xf = bf2f(*(const u16*)(xt + xb));
                Z[(size_t)(r0 + row) * N_OUT + gcol0] = Xf * __expf(Av) + Bv;
                part[m][j] += Av;
            }
            {
                float Av = aE1[m][j], Bv = aV1[m][j];
                int xb = (row * ROW_BYTES + (N_IN + gcol1) * 2) ^ swz;
                float Xf = bf2f(*(const u16*)(xt + xb));
                Z[(size_t)(r0 + row) * N_OUT + gcol1] = Xf * __expf(Av) + Bv;
                part[m][j] += Av;
            }
        }
    }
    // reduce over the 16 lanes (lr) sharing each row
    #pragma unroll
    for (int m = 0; m < 4; ++m) {
        #pragma unroll
        for (int j = 0; j < 4; ++j) {
            float v = part[m][j];
            v += __shfl_xor(v, 1);
            v += __shfl_xor(v, 2);
            v += __shfl_xor(v, 4);
            v += __shfl_xor(v, 8);
            if (lr == 0) ldsum[(wid << 6) + (m << 4) + (lg << 2) + j] = v;
        }
    }
    __syncthreads();
    if (tid < BM) {
        float s = 0.0f;
        #pragma unroll
        for (int w = 0; w < 8; ++w) s += ldsum[(w << 6) + tid];
        PS[(size_t)cb * BATCH + r0 + tid] = s;
    }
}

extern "C" void kernel_launch(void* const* d_in, const int* in_sizes, int n_in,
                              void* d_out, int out_size, void* d_ws, size_t ws_size,
                              hipStream_t stream) {
    const float* X  = (const float*)d_in[0];
    const float* Cc = (const float*)d_in[1];
    const float* PA = (const float*)d_in[2];
    const float* PB = (const float*)d_in[3];

    u16* WA = (u16*)d_ws;                                   // 589824 B
    u16* WB = WA + (size_t)N_OUT * D_TOT;                   // 589824 B
    float* PS = (float*)((char*)d_ws + 2 * (size_t)N_OUT * D_TOT * 2);  // 2*BATCH f32

    float* Z  = (float*)d_out;
    float* LD = Z + (size_t)BATCH * N_OUT;

    prep_weights_kernel<<<N_OUT, 256, 0, stream>>>(PA, PB, WA, WB);

    (void)hipFuncSetAttribute((const void*)maf_main_kernel,
                              hipFuncAttributeMaxDynamicSharedMemorySize,
                              LDS_TOTAL);
    const int grid = 2 * (BATCH / BM);    // 4096 (cb fastest-varying)
    maf_main_kernel<<<grid, 512, LDS_TOTAL, stream>>>(X, Cc, WA, WB, Z, PS);

    ld_merge_kernel<<<BATCH / 256, 256, 0, stream>>>(PS, LD);
}

// Round 12
// 346.605 us; speedup vs baseline: 1.0892x; 1.0892x over previous
//
#include <hip/hip_runtime.h>
#include <hip/hip_bf16.h>
#include <stdint.h>

#define N_OUT 512
#define N_IN 64
#define D_TOT 576               // N_IN + N_OUT
#define BM 128                  // batch rows per block
#define ROW_BYTES (D_TOT * 2)   // 1152 bytes per LDS x row (bf16)
#define XT_BYTES (BM * ROW_BYTES)      // 147456
#define LDS_TOTAL (XT_BYTES + 4 * BM * 4)  // + ldsum[4][128] = 149504

typedef __attribute__((ext_vector_type(8))) short short8_t;    // 8 x bf16 (4 VGPR)
typedef __attribute__((ext_vector_type(4))) float f32x4;
typedef __attribute__((ext_vector_type(16))) float f32x16;     // 32x32 acc
typedef unsigned short u16;

__device__ __forceinline__ u16 f2bf(float f) {
    __hip_bfloat16 h = __float2bfloat16(f);
    return *reinterpret_cast<u16*>(&h);
}
__device__ __forceinline__ float bf2f(u16 u) {
    union { uint32_t u; float f; } v;
    v.u = ((uint32_t)u) << 16;
    return v.f;
}

// Prep: masked bf16 weights, octet-k-major layout (unchanged since R2):
//   dst[(k/8)*512*8 + col*8 + (k%8)] = W[col][k]  (zero outside causal mask)
// Works for both 16x16x32 and 32x32x16 fragment addressing.
__global__ void prep_weights_kernel(const float* __restrict__ PA,
                                    const float* __restrict__ PB,
                                    u16* __restrict__ WA,
                                    u16* __restrict__ WB) {
    const int col = blockIdx.x;
    const int lim = N_IN + col;
    const float* pa = PA + (size_t)col * D_TOT;
    const float* pb = PB + (size_t)col * D_TOT;
    for (int k = threadIdx.x; k < D_TOT; k += blockDim.x) {
        size_t dst = (size_t)(k >> 3) * (N_OUT * 8) + (size_t)col * 8 + (k & 7);
        bool valid = (k < lim);
        WA[dst] = valid ? f2bf(pa[k]) : (u16)0;
        WB[dst] = valid ? f2bf(pb[k]) : (u16)0;
    }
}

// Main kernel. BM=128, 1024 threads (16 waves), 1 block/CU (146 KB LDS).
// R12 model: per-CU weight ingest (672 KB/block from L2 at ~56 B/cyc/CU) was
// the config-invariant wall at BM<=64. BM=128 cuts blocks/CU 16->4, weight
// bytes/CU 10.75->2.7 MB. mfma_32x32x16 keeps acc at 32 VGPR/wave so 16 waves
// (4/SIMD) fit under the 128-VGPR cap. Wave (rq,cw): rows rq*32..+31, col
// groups {cw,7-cw,8+cw,15-cw} (32 cols, ksteps=3+g causal). No K-loop barriers.
__global__ __launch_bounds__(1024)
void maf_main_kernel(const float* __restrict__ X,
                     const float* __restrict__ Cc,
                     const u16* __restrict__ WA,
                     const u16* __restrict__ WB,
                     float* __restrict__ Z,
                     float* __restrict__ LD) {
    extern __shared__ char smem[];
    char* xt = smem;                              // [128][1152] bf16, XOR-swizzled
    float* ldsum = (float*)(smem + XT_BYTES);     // [4][128]

    const int tid = threadIdx.x;
    const int r0 = blockIdx.x * BM;

    // ---- stage c (k in [0,64)) : 1024 chunks of 8 f32, 1 per thread ----
    {
        int row = tid >> 3, cc = tid & 7;
        const float* src = Cc + (size_t)(r0 + row) * N_IN + cc * 8;
        f32x4 v0 = __builtin_nontemporal_load((const f32x4*)src);
        f32x4 v1 = __builtin_nontemporal_load((const f32x4*)(src + 4));
        short8_t p;
        p[0] = (short)f2bf(v0[0]); p[1] = (short)f2bf(v0[1]);
        p[2] = (short)f2bf(v0[2]); p[3] = (short)f2bf(v0[3]);
        p[4] = (short)f2bf(v1[0]); p[5] = (short)f2bf(v1[1]);
        p[6] = (short)f2bf(v1[2]); p[7] = (short)f2bf(v1[3]);
        int addr = (row * ROW_BYTES + cc * 16) ^ ((row & 7) << 4);
        *(short8_t*)(xt + addr) = p;
    }
    // ---- stage X (k in [64,576)) : 8192 chunks, 8 per thread ----
    #pragma unroll
    for (int i = 0; i < 8; ++i) {
        int id = tid + i * 1024;
        int row = id >> 6, xc = id & 63;
        const float* src = X + (size_t)(r0 + row) * N_OUT + xc * 8;
        f32x4 v0 = __builtin_nontemporal_load((const f32x4*)src);
        f32x4 v1 = __builtin_nontemporal_load((const f32x4*)(src + 4));
        short8_t p;
        p[0] = (short)f2bf(v0[0]); p[1] = (short)f2bf(v0[1]);
        p[2] = (short)f2bf(v0[2]); p[3] = (short)f2bf(v0[3]);
        p[4] = (short)f2bf(v1[0]); p[5] = (short)f2bf(v1[1]);
        p[6] = (short)f2bf(v1[2]); p[7] = (short)f2bf(v1[3]);
        int addr = (row * ROW_BYTES + (8 + xc) * 16) ^ ((row & 7) << 4);
        *(short8_t*)(xt + addr) = p;
    }
    __syncthreads();

    const int wid  = tid >> 6;
    const int lane = tid & 63;
    const int cw = wid & 3;        // col-wave (4 per row-group)
    const int rq = wid >> 2;       // row-group (32 rows each)
    const int cl = lane & 31;      // col-in-group (B,C/D) / row-in-group (A)
    const int hi = lane >> 5;      // k-octet half (A,B) / row quad offset (C/D)

    const int rowBase = (rq << 5) + cl;
    const int aswz = (rowBase & 7) << 4;

    float part[16];                // per-lane log_det partials (reg r -> fixed row)
    #pragma unroll
    for (int r = 0; r < 16; ++r) part[r] = 0.0f;

    #pragma unroll
    for (int gi = 0; gi < 4; ++gi) {
        const int g = (gi == 0) ? cw : (gi == 1) ? 7 - cw : (gi == 2) ? 8 + cw : 15 - cw;
        const int ks = 3 + g;                 // causal: k < 64 + 32g + 32
        const int gc = (g << 5) + cl;         // global output col

        f32x16 aE = (f32x16)(0.0f);
        f32x16 aV = (f32x16)(0.0f);

        // weight base: octet hi, col gc -> u16 index (hi*512 + gc)*8
        const u16* wa = WA + ((size_t)hi * N_OUT + gc) * 8;
        const u16* wb = WB + ((size_t)hi * N_OUT + gc) * 8;

        for (int kk = 0; kk < ks; ++kk) {
            // A-fragments: rows rowBase, k-slices 2kk (bytes kk*64) and 2kk+1 (+32)
            const int ab = rowBase * ROW_BYTES + kk * 64 + (hi << 4);
            short8_t a0 = *(const short8_t*)(xt + (ab ^ aswz));
            short8_t a1 = *(const short8_t*)(xt + ((ab + 32) ^ aswz));
            // weights: octets 4kk+hi and 4kk+2+hi (kk stride = 4*512*8 u16)
            const u16* wak = wa + (size_t)kk * 16384;
            const u16* wbk = wb + (size_t)kk * 16384;
            short8_t e0 = *(const short8_t*)(wak);
            short8_t e1 = *(const short8_t*)(wak + 8192);
            short8_t v0 = *(const short8_t*)(wbk);
            short8_t v1 = *(const short8_t*)(wbk + 8192);
            aE = __builtin_amdgcn_mfma_f32_32x32x16_bf16(a0, e0, aE, 0, 0, 0);
            aE = __builtin_amdgcn_mfma_f32_32x32x16_bf16(a1, e1, aE, 0, 0, 0);
            aV = __builtin_amdgcn_mfma_f32_32x32x16_bf16(a0, v0, aV, 0, 0, 0);
            aV = __builtin_amdgcn_mfma_f32_32x32x16_bf16(a1, v1, aV, 0, 0, 0);
        }

        // ---- epilogue for this 32-col group ----
        // 32x32 C/D layout (verified m74/m101): col = lane&31,
        // row = (r&3) + 8*(r>>2) + 4*(lane>>5)
        #pragma unroll
        for (int r = 0; r < 16; ++r) {
            int row = (rq << 5) + (r & 3) + ((r >> 2) << 3) + (hi << 2);
            float Av = aE[r];
            float Bv = aV[r];
            int xb = (row * ROW_BYTES + (N_IN + gc) * 2) ^ ((row & 7) << 4);
            float Xf = bf2f(*(const u16*)(xt + xb));
            Z[(size_t)(r0 + row) * N_OUT + gc] = Xf * __expf(Av) + Bv;
            part[r] += Av;
        }
    }

    // ---- log_det: reduce over the 32 lanes (cl) sharing each (row,hi) ----
    #pragma unroll
    for (int r = 0; r < 16; ++r) {
        float v = part[r];
        v += __shfl_xor(v, 1);
        v += __shfl_xor(v, 2);
        v += __shfl_xor(v, 4);
        v += __shfl_xor(v, 8);
        v += __shfl_xor(v, 16);
        if (cl == 0) {
            int row = (rq << 5) + (r & 3) + ((r >> 2) << 3) + (hi << 2);
            ldsum[cw * BM + row] = v;   // cross-group accumulation is in part[]
        }
    }
    __syncthreads();
    if (tid < BM) {
        LD[(size_t)r0 + tid] = ldsum[tid] + ldsum[BM + tid]
                             + ldsum[2 * BM + tid] + ldsum[3 * BM + tid];
    }
}

extern "C" void kernel_launch(void* const* d_in, const int* in_sizes, int n_in,
                              void* d_out, int out_size, void* d_ws, size_t ws_size,
                              hipStream_t stream) {
    const float* X  = (const float*)d_in[0];
    const float* Cc = (const float*)d_in[1];
    const float* PA = (const float*)d_in[2];
    const float* PB = (const float*)d_in[3];

    u16* WA = (u16*)d_ws;                          // 512*576*2 bytes (octet-k-major)
    u16* WB = WA + (size_t)N_OUT * D_TOT;

    float* Z  = (float*)d_out;
    const size_t batch = (size_t)in_sizes[0] / N_OUT;   // 131072
    float* LD = Z + batch * N_OUT;

    prep_weights_kernel<<<N_OUT, 256, 0, stream>>>(PA, PB, WA, WB);

    (void)hipFuncSetAttribute((const void*)maf_main_kernel,
                              hipFuncAttributeMaxDynamicSharedMemorySize,
                              LDS_TOTAL);
    const int grid = (int)(batch / BM);            // 1024
    maf_main_kernel<<<grid, 1024, LDS_TOTAL, stream>>>(X, Cc, WA, WB, Z, LD);
}